// Round 8
// baseline (690.589 us; speedup 1.0000x reference)
//
#include <hip/hip_runtime.h>
#include <stdint.h>

#define T_ 2048
#define V_ 32000
#define D_ 1024
#define E_ 16
#define CAP_ 256
#define DFF_ 2048

typedef unsigned short u16;
typedef unsigned int u32;
typedef __bf16 bf16x8 __attribute__((ext_vector_type(8)));
typedef float f32x4 __attribute__((ext_vector_type(4)));

__device__ __forceinline__ u16 f2bf(float f){
  u32 u = __float_as_uint(f);
  u32 r = u + 0x7FFFu + ((u >> 16) & 1u);
  return (u16)(r >> 16);
}
__device__ __forceinline__ float bf2f(u16 s){ return __uint_as_float(((u32)s) << 16); }

__device__ __forceinline__ void gl_lds16(const void* g, void* l){
  __builtin_amdgcn_global_load_lds((const __attribute__((address_space(1))) void*)g,
                                   (__attribute__((address_space(3))) void*)l, 16, 0, 0);
}
__device__ __forceinline__ f32x4 mfma16(bf16x8 a, bf16x8 b, f32x4 c){
  return __builtin_amdgcn_mfma_f32_16x16x32_bf16(a, b, c, 0, 0, 0);
}
__device__ __forceinline__ float gelu_tanh(float x){
  float u = 0.7978845608028654f * (x + 0.044715f * x * x * x);
  return 0.5f * x * (1.0f + tanhf(u));
}

// ---------------- embed_W fp32 -> bf16 ----------------
__global__ __launch_bounds__(256) void k_cvtw(const float* __restrict__ W, u16* __restrict__ Wb){
  size_t i = ((size_t)blockIdx.x*256 + threadIdx.x)*8;
  float4 a = *(const float4*)(W + i);
  float4 b = *(const float4*)(W + i + 4);
  union { u16 s[8]; uint4 v; } p;
  p.s[0]=f2bf(a.x); p.s[1]=f2bf(a.y); p.s[2]=f2bf(a.z); p.s[3]=f2bf(a.w);
  p.s[4]=f2bf(b.x); p.s[5]=f2bf(b.y); p.s[6]=f2bf(b.z); p.s[7]=f2bf(b.w);
  *(uint4*)(Wb + i) = p.v;
}

// ---------------- router (+etok init; optionally fused embedding) ----------------
template<bool EMB>
__global__ __launch_bounds__(256) void k_router(float* __restrict__ h,
    const float* __restrict__ Wr, float* __restrict__ logits,
    unsigned char* __restrict__ mask, int* __restrict__ top2, float* __restrict__ p2,
    const int* __restrict__ ids, const float* __restrict__ embW, int* __restrict__ etok){
  if (blockIdx.x < (E_*CAP_)/256) etok[blockIdx.x*256 + threadIdx.x] = -1;
  int w = threadIdx.x >> 6, l = threadIdx.x & 63;
  int t = blockIdx.x*4 + w;
  float acc[E_];
  #pragma unroll
  for (int e=0;e<E_;++e) acc[e]=0.f;
  const float* hrow = EMB ? (embW + (size_t)ids[t]*D_) : (h + (size_t)t*D_);
  #pragma unroll
  for (int i=0;i<16;++i){
    int d = l + i*64;
    float hv = hrow[d];
    if (EMB) h[(size_t)t*D_ + d] = hv;
    const float4* wr = (const float4*)(Wr + d*E_);
    float4 w0=wr[0], w1=wr[1], w2=wr[2], w3=wr[3];
    acc[0]+=hv*w0.x; acc[1]+=hv*w0.y; acc[2]+=hv*w0.z; acc[3]+=hv*w0.w;
    acc[4]+=hv*w1.x; acc[5]+=hv*w1.y; acc[6]+=hv*w1.z; acc[7]+=hv*w1.w;
    acc[8]+=hv*w2.x; acc[9]+=hv*w2.y; acc[10]+=hv*w2.z; acc[11]+=hv*w2.w;
    acc[12]+=hv*w3.x; acc[13]+=hv*w3.y; acc[14]+=hv*w3.z; acc[15]+=hv*w3.w;
  }
  #pragma unroll
  for (int off=32; off; off>>=1){
    #pragma unroll
    for (int e=0;e<E_;++e) acc[e] += __shfl_xor(acc[e], off, 64);
  }
  float mx = acc[0];
  #pragma unroll
  for (int e=1;e<E_;++e) mx = fmaxf(mx, acc[e]);
  float p[E_], s = 0.f;
  #pragma unroll
  for (int e=0;e<E_;++e){ p[e] = expf(acc[e]-mx); s += p[e]; }
  int i1 = 0; float v1 = acc[0];
  #pragma unroll
  for (int e=1;e<E_;++e) if (acc[e] > v1){ v1 = acc[e]; i1 = e; }
  int i2 = (i1==0)?1:0; float v2 = acc[i2];
  #pragma unroll
  for (int e=0;e<E_;++e) if (e!=i1 && e!=i2 && acc[e] > v2){ v2 = acc[e]; i2 = e; }
  if (l < E_){
    logits[t*E_+l] = acc[l];
    mask[t*E_+l] = (l==i1 || l==i2) ? 1 : 0;
  }
  if (l == 0){
    float inv = 1.f/s;
    top2[t*2] = i1; top2[t*2+1] = i2;
    p2[t*2] = p[i1]*inv; p2[t*2+1] = p[i2]*inv;
  }
}

// ---------------- capacity selection ----------------
__global__ __launch_bounds__(256) void k_capacity(const float* __restrict__ logits,
    const unsigned char* __restrict__ mask, const int* __restrict__ top2,
    int* __restrict__ kept, int* __restrict__ etok){
  int w = threadIdx.x >> 6, l = threadIdx.x & 63;
  int wid = blockIdx.x*4 + w;
  int t = wid >> 1, k = wid & 1;
  int e = top2[t*2+k];
  float my = logits[t*E_+e];
  int cnt = 0;
  for (int t2 = l; t2 < T_; t2 += 64){
    if (mask[t2*E_+e]){
      float lg = logits[t2*E_+e];
      if (lg > my || (lg == my && t2 < t)) cnt++;
    }
  }
  #pragma unroll
  for (int off=32; off; off>>=1) cnt += __shfl_xor(cnt, off, 64);
  if (l == 0){
    if (cnt < CAP_){ kept[t*2+k] = cnt; etok[e*CAP_+cnt] = t; }
    else kept[t*2+k] = -1;
  }
}

// ---------------- gather ----------------
template<bool SPLIT>
__global__ __launch_bounds__(256) void k_gather(const float* __restrict__ h,
    const int* __restrict__ etok, u16* __restrict__ xhi, u16* __restrict__ xlo){
  int rc = blockIdx.x;
  int tok = etok[rc];
  int d = threadIdx.x * 4;
  float4 v = make_float4(0.f,0.f,0.f,0.f);
  if (tok >= 0) v = *(const float4*)(h + (size_t)tok*D_ + d);
  union { u16 s[4]; uint2 u; } hi, lo;
  hi.s[0]=f2bf(v.x); lo.s[0]=f2bf(v.x - bf2f(hi.s[0]));
  hi.s[1]=f2bf(v.y); lo.s[1]=f2bf(v.y - bf2f(hi.s[1]));
  hi.s[2]=f2bf(v.z); lo.s[2]=f2bf(v.z - bf2f(hi.s[2]));
  hi.s[3]=f2bf(v.w); lo.s[3]=f2bf(v.w - bf2f(hi.s[3]));
  *(uint2*)(xhi + (size_t)rc*D_ + d) = hi.u;
  if (SPLIT) *(uint2*)(xlo + (size_t)rc*D_ + d) = lo.u;
}

// ---------------- expert GEMM v2 + vectorized (LDS-transposed) epilogue ----------------
template<bool SPLIT, bool GELU, int BN>
__global__ __launch_bounds__(512, 1) void k_expert(
    const u16* __restrict__ Ahi, const u16* __restrict__ Alo,
    const float* __restrict__ Bw,
    u16* __restrict__ Ohi, u16* __restrict__ Olo, float* __restrict__ Of,
    int N, int K){
  constexpr int NI = BN/64;
  constexpr int ABYTES = 2*16384*(SPLIT?2:1);
  constexpr int BSLOT = BN*80;
  constexpr int BBYTES = 2*BSLOT*(SPLIT?2:1);
  __shared__ __align__(16) char sm[ABYTES + BBYTES];
  char* smA   = sm;
  char* smALo = sm + 32768;
  char* smB   = sm + ABYTES;
  char* smBLo = sm + ABYTES + 2*BSLOT;

  int bid = blockIdx.x;
  int swz = (bid & 7)*32 + (bid >> 3);
  int e  = swz >> 4;
  int n0 = (swz & 15) * BN;
  int tid = threadIdx.x;
  int lane = tid & 63;
  int w = tid >> 6;
  int wm = w >> 2, wn = w & 3;
  int lr = lane & 15, lq = lane >> 4;
  int NK = K >> 5;

  const u16* Ah = Ahi + (size_t)e*256*K;
  const u16* Al = SPLIT ? (Alo + (size_t)e*256*K) : (const u16*)nullptr;
  const float* Bb = Bw + (size_t)e*K*N + n0;

  f32x4 acc[8][NI];
  #pragma unroll
  for (int i=0;i<8;++i)
    #pragma unroll
    for (int j=0;j<NI;++j)
      #pragma unroll
      for (int c=0;c<4;++c) acc[i][j][c] = 0.f;

  int t2 = tid - 256;
  const u16* aSrcH[4]; const u16* aSrcL[4]; int aDst[4];
  #pragma unroll
  for (int r=0;r<4;++r){
    int o = r*4096 + t2*16;
    int row = o >> 6;
    int cs = ((o >> 4) & 3) ^ ((row >> 1) & 3);
    aDst[r] = o;
    aSrcH[r] = Ah + (size_t)row*K + cs*8;
    if (SPLIT) aSrcL[r] = Al + (size_t)row*K + cs*8;
  }
  int kb = (BN==128) ? (tid>>5) : (tid>>4);
  int nb = (BN==128) ? (tid&31) : (tid&15);
  int wOff[4];
  #pragma unroll
  for (int j=0;j<4;++j){
    int n = nb*4 + j;
    int pos;
    if (BN==128) pos = ((kb ^ (2*(nb&3))) & 7) * 8;
    else         pos = (kb*4) ^ ((nb&3)*16);
    wOff[j] = n*80 + pos;
  }
  float4 pb[4];

  #define LOADPB_(k0n) do { \
    if constexpr (BN==128){ \
      const float* bp = Bb + (size_t)((k0n) + kb*4)*N + nb*4; \
      pb[0] = *(const float4*)bp; pb[1] = *(const float4*)(bp + N); \
      pb[2] = *(const float4*)(bp + 2*N); pb[3] = *(const float4*)(bp + 3*N); \
    } else { \
      const float* bp = Bb + (size_t)((k0n) + kb*2)*N + nb*4; \
      pb[0] = *(const float4*)bp; pb[1] = *(const float4*)(bp + N); \
    } } while(0)

  #define WRITEB_(slot) do { \
    char* bh_ = smB + (slot)*BSLOT; char* bl_ = smBLo + (slot)*BSLOT; \
    if constexpr (BN==128){ \
      float cv[4][4] = {{pb[0].x,pb[1].x,pb[2].x,pb[3].x},{pb[0].y,pb[1].y,pb[2].y,pb[3].y}, \
                        {pb[0].z,pb[1].z,pb[2].z,pb[3].z},{pb[0].w,pb[1].w,pb[2].w,pb[3].w}}; \
      _Pragma("unroll") for (int j=0;j<4;++j){ \
        union { u16 s[4]; uint2 u; } hi, lo; \
        _Pragma("unroll") for (int i=0;i<4;++i){ \
          hi.s[i] = f2bf(cv[j][i]); \
          if constexpr (SPLIT) lo.s[i] = f2bf(cv[j][i] - bf2f(hi.s[i])); } \
        *(uint2*)(bh_ + wOff[j]) = hi.u; \
        if constexpr (SPLIT) *(uint2*)(bl_ + wOff[j]) = lo.u; } \
    } else { \
      float cv[4][2] = {{pb[0].x,pb[1].x},{pb[0].y,pb[1].y},{pb[0].z,pb[1].z},{pb[0].w,pb[1].w}}; \
      _Pragma("unroll") for (int j=0;j<4;++j){ \
        union { u16 s[2]; u32 u; } hi, lo; \
        _Pragma("unroll") for (int i=0;i<2;++i){ \
          hi.s[i] = f2bf(cv[j][i]); \
          if constexpr (SPLIT) lo.s[i] = f2bf(cv[j][i] - bf2f(hi.s[i])); } \
        *(u32*)(bh_ + wOff[j]) = hi.u; \
        if constexpr (SPLIT) *(u32*)(bl_ + wOff[j]) = lo.u; } \
    } } while(0)

  #define STAGEA_(k0n, slot) do { \
    _Pragma("unroll") for (int r=0;r<4;++r){ \
      gl_lds16(aSrcH[r] + (k0n), smA + (slot)*16384 + aDst[r]); \
      if constexpr (SPLIT) gl_lds16(aSrcL[r] + (k0n), smALo + (slot)*16384 + aDst[r]); \
    } } while(0)

  if (tid < 256){
    LOADPB_(0);
    WRITEB_(0);
    if (NK > 1) LOADPB_(32);
  } else {
    STAGEA_(0, 0);
  }
  __syncthreads();

  int aRo[8];
  #pragma unroll
  for (int mi=0;mi<8;++mi){
    int row = wm*128 + mi*16 + lr;
    aRo[mi] = row*64 + ((lq ^ ((row>>1)&3))<<4);
  }
  int bRo[NI];
  #pragma unroll
  for (int ni=0;ni<NI;++ni){
    int n = wn*(BN/4) + ni*16 + lr;
    bRo[ni] = n*80 + ((lq ^ ((n>>2)&3))<<4);
  }

  for (int ks = 0; ks < NK; ++ks){
    int cur = ks & 1;
    bf16x8 bh[NI], bl[NI];
    #pragma unroll
    for (int ni=0;ni<NI;++ni){
      bh[ni] = *(const bf16x8*)(smB + cur*BSLOT + bRo[ni]);
      if constexpr (SPLIT) bl[ni] = *(const bf16x8*)(smBLo + cur*BSLOT + bRo[ni]);
    }
    if (ks + 1 < NK){
      int nslot = cur ^ 1;
      if (tid < 256){
        WRITEB_(nslot);
        if (ks + 2 < NK) LOADPB_((ks+2)*32);
      } else {
        STAGEA_((ks+1)*32, nslot);
      }
    }
    #pragma unroll
    for (int mi=0;mi<8;++mi){
      bf16x8 ah = *(const bf16x8*)(smA + cur*16384 + aRo[mi]);
      if constexpr (SPLIT){
        bf16x8 al = *(const bf16x8*)(smALo + cur*16384 + aRo[mi]);
        #pragma unroll
        for (int ni=0;ni<NI;++ni){
          acc[mi][ni] = mfma16(ah, bh[ni], acc[mi][ni]);
          acc[mi][ni] = mfma16(al, bh[ni], acc[mi][ni]);
          acc[mi][ni] = mfma16(ah, bl[ni], acc[mi][ni]);
        }
      } else {
        #pragma unroll
        for (int ni=0;ni<NI;++ni)
          acc[mi][ni] = mfma16(ah, bh[ni], acc[mi][ni]);
      }
    }
    __syncthreads();
  }
  #undef LOADPB_
  #undef WRITEB_
  #undef STAGEA_

  // ---- epilogue: per-wave LDS transpose -> vectorized stores ----
  {
    constexpr int STRIPB = NI*16*4*16;
    char* strip = sm + w*STRIPB;
    int r = lane & 15;
    int b = lane >> 4;
    #pragma unroll
    for (int mi=0;mi<8;++mi){
      #pragma unroll
      for (int ni=0;ni<NI;++ni){
        int col = ni*16 + lr;
        f32x4 v = acc[mi][ni];
        if constexpr (GELU){
          v[0]=gelu_tanh(v[0]); v[1]=gelu_tanh(v[1]);
          v[2]=gelu_tanh(v[2]); v[3]=gelu_tanh(v[3]);
        }
        *(f32x4*)(strip + (col*4 + lq)*16) = v;
      }
      asm volatile("s_waitcnt lgkmcnt(0)" ::: "memory");
      __builtin_amdgcn_sched_barrier(0);
      int grow = wm*128 + mi*16 + r;
      if constexpr (GELU){
        union { u16 s[8]; uint4 v; } ph, pl;
        #pragma unroll
        for (int i=0;i<8;++i){
          float y = *(const float*)(strip + ((b*8+i)*4 + (r>>2))*16 + (r&3)*4);
          ph.s[i] = f2bf(y);
          if constexpr (SPLIT) pl.s[i] = f2bf(y - bf2f(ph.s[i]));
        }
        size_t idx = ((size_t)e*256 + grow)*N + n0 + wn*(BN/4) + b*8;
        *(uint4*)(Ohi + idx) = ph.v;
        if constexpr (SPLIT) *(uint4*)(Olo + idx) = pl.v;
      } else {
        #pragma unroll
        for (int cc=0; cc<NI; ++cc){
          int c = b + cc*4;
          float4 o;
          o.x = *(const float*)(strip + ((c*4+0)*4 + (r>>2))*16 + (r&3)*4);
          o.y = *(const float*)(strip + ((c*4+1)*4 + (r>>2))*16 + (r&3)*4);
          o.z = *(const float*)(strip + ((c*4+2)*4 + (r>>2))*16 + (r&3)*4);
          o.w = *(const float*)(strip + ((c*4+3)*4 + (r>>2))*16 + (r&3)*4);
          *(float4*)(Of + ((size_t)e*256 + grow)*N + n0 + wn*(BN/4) + c*4) = o;
        }
      }
      asm volatile("s_waitcnt lgkmcnt(0)" ::: "memory");
    }
  }
}

// ---------------- combine (optionally fused RMSNorm -> bf16) ----------------
template<bool FINAL>
__global__ __launch_bounds__(256) void k_combine(float* __restrict__ h,
    const float* __restrict__ Y2, const int* __restrict__ top2,
    const float* __restrict__ p2, const int* __restrict__ kept,
    const float* __restrict__ g, u16* __restrict__ hn){
  int t = blockIdx.x;
  int e0 = top2[t*2], e1 = top2[t*2+1];
  int r0 = kept[t*2], r1 = kept[t*2+1];
  float w0 = (r0 >= 0) ? p2[t*2]   : 0.f;
  float w1 = (r1 >= 0) ? p2[t*2+1] : 0.f;
  float om = 1.f - w0 - w1;
  int d = threadIdx.x * 4;
  float4 v = *(const float4*)(h + (size_t)t*D_ + d);
  float ox = v.x*om, oy = v.y*om, oz = v.z*om, ow = v.w*om;
  if (r0 >= 0){
    float4 y = *(const float4*)(Y2 + ((size_t)e0*CAP_ + r0)*D_ + d);
    ox += w0*y.x; oy += w0*y.y; oz += w0*y.z; ow += w0*y.w;
  }
  if (r1 >= 0){
    float4 y = *(const float4*)(Y2 + ((size_t)e1*CAP_ + r1)*D_ + d);
    ox += w1*y.x; oy += w1*y.y; oz += w1*y.z; ow += w1*y.w;
  }
  if constexpr (!FINAL){
    *(float4*)(h + (size_t)t*D_ + d) = make_float4(ox, oy, oz, ow);
  } else {
    int w = threadIdx.x >> 6, l = threadIdx.x & 63;
    __shared__ float red[4];
    float ss = ox*ox + oy*oy + oz*oz + ow*ow;
    #pragma unroll
    for (int off=32; off; off>>=1) ss += __shfl_xor(ss, off, 64);
    if (l == 0) red[w] = ss;
    __syncthreads();
    float tot = red[0] + red[1] + red[2] + red[3];
    float sc = rsqrtf(tot * (1.f/D_) + 1e-5f);
    float4 gs = *(const float4*)(g + d);
    union { u16 s[4]; uint2 u; } o;
    o.s[0] = f2bf(ox*sc*gs.x); o.s[1] = f2bf(oy*sc*gs.y);
    o.s[2] = f2bf(oz*sc*gs.z); o.s[3] = f2bf(ow*sc*gs.w);
    *(uint2*)(hn + (size_t)t*D_ + d) = o.u;
  }
}

// ---------------- final GEMM v5b: 128x128 tile, 256 thr (4 waves 2x2),
// ring-4 BK=32 slots, 64 KB LDS -> 2 blocks/CU.
// FIX vs v5: gl_lds LDS dest must be wave-uniform-base + lane*16 (HW linear
// write). Each wave issues 2 contiguous 1024B calls per operand:
//   dest d_j = w*2048 + j*1024 + lane*16
//   covered row = w*32 + j*16 + (lane>>2), chunk c = lane&3
//   source chunk cs = c ^ ((row>>1)&3)  (inverse swizzle; read side XORs back)
#define FSLOT_ 8192
__global__ __launch_bounds__(256, 2) void k_gemm_final(const u16* __restrict__ A,
    const u16* __restrict__ B, float* __restrict__ C){
  __shared__ __align__(16) char lds[65536];
  char* ldsA = lds;             // 4 slots x 8 KB
  char* ldsB = lds + 32768;     // 4 slots x 8 KB
  int bid = blockIdx.x;
  int swz = (bid & 7)*500 + (bid >> 3);   // 4000 = 8*500, bijective
  int m0 = (swz & 15) << 7;               // m fastest: B-panel L2 reuse
  int n0 = (swz >> 4) << 7;
  int tid = threadIdx.x;
  int lane = tid & 63;
  int w = tid >> 6;             // 4 waves
  int wm = w >> 1, wn = w & 1;  // 2x2, wave tile 64x64
  int lr = lane & 15, lq = lane >> 4;

  f32x4 acc[4][4];
  #pragma unroll
  for (int i=0;i<4;++i)
    #pragma unroll
    for (int j=0;j<4;++j)
      #pragma unroll
      for (int c=0;c<4;++c) acc[i][j][c] = 0.f;

  // staging (gl_lds-linear): wave w, call j covers LDS bytes w*2048+j*1024 + lane*16
  int row0 = w*32 + (lane >> 2);
  int row1 = row0 + 16;
  int c = lane & 3;
  int cs0 = c ^ ((row0 >> 1) & 3);
  int cs1 = c ^ ((row1 >> 1) & 3);
  const u16* sA0 = A + (size_t)(m0+row0)*D_ + cs0*8;
  const u16* sA1 = A + (size_t)(m0+row1)*D_ + cs1*8;
  const u16* sB0 = B + (size_t)(n0+row0)*D_ + cs0*8;
  const u16* sB1 = B + (size_t)(n0+row1)*D_ + cs1*8;
  int d0 = w*2048 + lane*16;
  int d1 = d0 + 1024;

  // frag read offsets (slot-invariant): LDS chunk (lq ^ ((r>>1)&3)) holds global chunk lq
  int aoff[4], boff[4];
  #pragma unroll
  for (int mi=0;mi<4;++mi){
    int r = wm*64 + mi*16 + lr;
    aoff[mi] = r*64 + ((lq ^ ((r>>1)&3))<<4);
  }
  #pragma unroll
  for (int ni=0;ni<4;++ni){
    int r = wn*64 + ni*16 + lr;
    boff[ni] = r*64 + ((lq ^ ((r>>1)&3))<<4);
  }

  #define STAGE_(slot) do { \
    gl_lds16(sA0, ldsA + (slot)*FSLOT_ + d0); gl_lds16(sB0, ldsB + (slot)*FSLOT_ + d0); \
    gl_lds16(sA1, ldsA + (slot)*FSLOT_ + d1); gl_lds16(sB1, ldsB + (slot)*FSLOT_ + d1); \
    sA0 += 32; sA1 += 32; sB0 += 32; sB1 += 32; } while(0)

  #define READF_(slot, FA, FB) do { \
    const char* pA_ = ldsA + (slot)*FSLOT_; const char* pB_ = ldsB + (slot)*FSLOT_; \
    _Pragma("unroll") for (int ni=0;ni<4;++ni) FB[ni] = *(const bf16x8*)(pB_ + boff[ni]); \
    _Pragma("unroll") for (int mi=0;mi<4;++mi) FA[mi] = *(const bf16x8*)(pA_ + aoff[mi]); \
  } while(0)

  bf16x8 aF0[4], bF0[4], aF1[4], bF1[4];

  // prologue: stage slots 0,1,2; confirm slot 0; read it.
  STAGE_(0); STAGE_(1); STAGE_(2);
  asm volatile("s_waitcnt vmcnt(8)" ::: "memory");
  __builtin_amdgcn_s_barrier();
  READF_(0, aF0, bF0);

  #define PHASE_(kh, FAc, FBc, FAn, FBn) do { \
    if ((kh) <= 28) STAGE_(((kh)+3)&3); \
    if ((kh) <= 28)      asm volatile("s_waitcnt vmcnt(8)" ::: "memory"); \
    else if ((kh) == 29) asm volatile("s_waitcnt vmcnt(4)" ::: "memory"); \
    else if ((kh) == 30) asm volatile("s_waitcnt vmcnt(0)" ::: "memory"); \
    asm volatile("s_waitcnt lgkmcnt(0)" ::: "memory"); \
    __builtin_amdgcn_sched_barrier(0); \
    __builtin_amdgcn_s_barrier(); \
    __builtin_amdgcn_sched_barrier(0); \
    if ((kh) < 31) READF_(((kh)+1)&3, FAn, FBn); \
    __builtin_amdgcn_s_setprio(1); \
    _Pragma("unroll") for (int mi=0;mi<4;++mi){ \
      _Pragma("unroll") for (int ni=0;ni<4;++ni) \
        acc[mi][ni] = mfma16(FAc[mi], FBc[ni], acc[mi][ni]); \
    } \
    __builtin_amdgcn_s_setprio(0); \
  } while(0)

  for (int kh2 = 0; kh2 < 32; kh2 += 2){
    PHASE_(kh2,     aF0, bF0, aF1, bF1);
    PHASE_(kh2 + 1, aF1, bF1, aF0, bF0);
  }
  #undef PHASE_
  #undef READF_
  #undef STAGE_

  #pragma unroll
  for (int mi=0;mi<4;++mi)
    #pragma unroll
    for (int ni=0;ni<4;++ni)
      #pragma unroll
      for (int j=0;j<4;++j){
        int row = m0 + wm*64 + mi*16 + lq*4 + j;
        int col = n0 + wn*64 + ni*16 + lr;
        C[(size_t)row * V_ + col] = acc[mi][ni][j];
      }
}

extern "C" void kernel_launch(void* const* d_in, const int* in_sizes, int n_in,
                              void* d_out, int out_size, void* d_ws, size_t ws_size,
                              hipStream_t stream){
  const int*   ids  = (const int*)d_in[0];
  const float* embW = (const float*)d_in[1];
  const float* lns  = (const float*)d_in[2];
  const float* WrA  = (const float*)d_in[3];
  const float* W1A  = (const float*)d_in[4];
  const float* W2A  = (const float*)d_in[5];
  float* out = (float*)d_out;
  char* ws = (char*)d_ws;
  const size_t MB = 1u << 20;

  float* h      = (float*)(ws);
  float* logits = (float*)(ws + 8*MB);
  unsigned char* mask = (unsigned char*)(ws + 8*MB + 131072);
  int*   top2v  = (int*)(ws + 8*MB + 131072 + 32768);
  float* p2     = (float*)(ws + 8*MB + 131072 + 32768 + 16384);
  int*   kept   = (int*)(ws + 8*MB + 131072 + 32768 + 32768);
  int*   etok   = (int*)(ws + 8*MB + 131072 + 32768 + 49152);
  u16*   xhi  = (u16*)(ws + 9*MB);
  u16*   xlo  = (u16*)(ws + 17*MB);
  float* y2   = (float*)(ws + 9*MB);            // aliases xhi/xlo (dead by then)
  u16*   y1hi = (u16*)(ws + 25*MB);
  u16*   y1lo = (u16*)(ws + 41*MB);
  u16*   hn   = (u16*)(ws + 57*MB);
  u16*   ebf  = (u16*)(ws + 61*MB);

  k_cvtw<<<(V_*D_)/(256*8), 256, 0, stream>>>(embW, ebf);

  for (int hop = 0; hop < 2; ++hop){
    const float* Wr = WrA + (size_t)hop*D_*E_;
    const float* W1 = W1A + (size_t)hop*E_*D_*DFF_;
    const float* W2 = W2A + (size_t)hop*E_*DFF_*D_;
    if (hop == 0){
      k_router<true ><<<T_/4, 256, 0, stream>>>(h, Wr, logits, mask, top2v, p2, ids, embW, etok);
      k_capacity<<<T_*2/4, 256, 0, stream>>>(logits, mask, top2v, kept, etok);
      k_gather<true ><<<E_*CAP_, 256, 0, stream>>>(h, etok, xhi, xlo);
      k_expert<true , true , 128><<<E_*(DFF_/128), 512, 0, stream>>>(
          xhi, xlo, W1, y1hi, y1lo, nullptr, DFF_, D_);
      k_expert<true , false, 64 ><<<E_*(D_/64), 512, 0, stream>>>(
          y1hi, y1lo, W2, nullptr, nullptr, y2, D_, DFF_);
      k_combine<false><<<T_, 256, 0, stream>>>(h, y2, top2v, p2, kept, lns, hn);
    } else {
      k_router<false><<<T_/4, 256, 0, stream>>>(h, Wr, logits, mask, top2v, p2, ids, embW, etok);
      k_capacity<<<T_*2/4, 256, 0, stream>>>(logits, mask, top2v, kept, etok);
      k_gather<false><<<E_*CAP_, 256, 0, stream>>>(h, etok, xhi, xlo);
      k_expert<false, true , 128><<<E_*(DFF_/128), 512, 0, stream>>>(
          xhi, nullptr, W1, y1hi, nullptr, nullptr, DFF_, D_);
      k_expert<false, false, 64 ><<<E_*(D_/64), 512, 0, stream>>>(
          y1hi, nullptr, W2, nullptr, nullptr, y2, D_, DFF_);
      k_combine<true ><<<T_, 256, 0, stream>>>(h, y2, top2v, p2, kept, lns, hn);
    }
  }

  k_gemm_final<<<(T_/128)*(V_/128), 256, 0, stream>>>(hn, ebf, out);
}

// Round 9
// 641.852 us; speedup vs baseline: 1.0759x; 1.0759x over previous
//
#include <hip/hip_runtime.h>
#include <stdint.h>

#define T_ 2048
#define V_ 32000
#define D_ 1024
#define E_ 16
#define CAP_ 256
#define DFF_ 2048

typedef unsigned short u16;
typedef unsigned int u32;
typedef __bf16 bf16x8 __attribute__((ext_vector_type(8)));
typedef float f32x4 __attribute__((ext_vector_type(4)));

__device__ __forceinline__ u16 f2bf(float f){
  u32 u = __float_as_uint(f);
  u32 r = u + 0x7FFFu + ((u >> 16) & 1u);
  return (u16)(r >> 16);
}
__device__ __forceinline__ float bf2f(u16 s){ return __uint_as_float(((u32)s) << 16); }

__device__ __forceinline__ void gl_lds16(const void* g, void* l){
  __builtin_amdgcn_global_load_lds((const __attribute__((address_space(1))) void*)g,
                                   (__attribute__((address_space(3))) void*)l, 16, 0, 0);
}
__device__ __forceinline__ f32x4 mfma16(bf16x8 a, bf16x8 b, f32x4 c){
  return __builtin_amdgcn_mfma_f32_16x16x32_bf16(a, b, c, 0, 0, 0);
}
__device__ __forceinline__ void nt_store4(float* p, f32x4 v){
  __builtin_nontemporal_store(v, (f32x4*)p);
}
__device__ __forceinline__ float gelu_tanh(float x){
  float u = 0.7978845608028654f * (x + 0.044715f * x * x * x);
  return 0.5f * x * (1.0f + tanhf(u));
}

// ---------------- embed_W fp32 -> bf16 ----------------
__global__ __launch_bounds__(256) void k_cvtw(const float* __restrict__ W, u16* __restrict__ Wb){
  size_t i = ((size_t)blockIdx.x*256 + threadIdx.x)*8;
  float4 a = *(const float4*)(W + i);
  float4 b = *(const float4*)(W + i + 4);
  union { u16 s[8]; uint4 v; } p;
  p.s[0]=f2bf(a.x); p.s[1]=f2bf(a.y); p.s[2]=f2bf(a.z); p.s[3]=f2bf(a.w);
  p.s[4]=f2bf(b.x); p.s[5]=f2bf(b.y); p.s[6]=f2bf(b.z); p.s[7]=f2bf(b.w);
  *(uint4*)(Wb + i) = p.v;
}

// ---------------- router (+etok init; optionally fused embedding) ----------------
template<bool EMB>
__global__ __launch_bounds__(256) void k_router(float* __restrict__ h,
    const float* __restrict__ Wr, float* __restrict__ logits,
    unsigned char* __restrict__ mask, int* __restrict__ top2, float* __restrict__ p2,
    const int* __restrict__ ids, const float* __restrict__ embW, int* __restrict__ etok){
  if (blockIdx.x < (E_*CAP_)/256) etok[blockIdx.x*256 + threadIdx.x] = -1;
  int w = threadIdx.x >> 6, l = threadIdx.x & 63;
  int t = blockIdx.x*4 + w;
  float acc[E_];
  #pragma unroll
  for (int e=0;e<E_;++e) acc[e]=0.f;
  const float* hrow = EMB ? (embW + (size_t)ids[t]*D_) : (h + (size_t)t*D_);
  #pragma unroll
  for (int i=0;i<16;++i){
    int d = l + i*64;
    float hv = hrow[d];
    if (EMB) h[(size_t)t*D_ + d] = hv;
    const float4* wr = (const float4*)(Wr + d*E_);
    float4 w0=wr[0], w1=wr[1], w2=wr[2], w3=wr[3];
    acc[0]+=hv*w0.x; acc[1]+=hv*w0.y; acc[2]+=hv*w0.z; acc[3]+=hv*w0.w;
    acc[4]+=hv*w1.x; acc[5]+=hv*w1.y; acc[6]+=hv*w1.z; acc[7]+=hv*w1.w;
    acc[8]+=hv*w2.x; acc[9]+=hv*w2.y; acc[10]+=hv*w2.z; acc[11]+=hv*w2.w;
    acc[12]+=hv*w3.x; acc[13]+=hv*w3.y; acc[14]+=hv*w3.z; acc[15]+=hv*w3.w;
  }
  #pragma unroll
  for (int off=32; off; off>>=1){
    #pragma unroll
    for (int e=0;e<E_;++e) acc[e] += __shfl_xor(acc[e], off, 64);
  }
  float mx = acc[0];
  #pragma unroll
  for (int e=1;e<E_;++e) mx = fmaxf(mx, acc[e]);
  float p[E_], s = 0.f;
  #pragma unroll
  for (int e=0;e<E_;++e){ p[e] = expf(acc[e]-mx); s += p[e]; }
  int i1 = 0; float v1 = acc[0];
  #pragma unroll
  for (int e=1;e<E_;++e) if (acc[e] > v1){ v1 = acc[e]; i1 = e; }
  int i2 = (i1==0)?1:0; float v2 = acc[i2];
  #pragma unroll
  for (int e=0;e<E_;++e) if (e!=i1 && e!=i2 && acc[e] > v2){ v2 = acc[e]; i2 = e; }
  if (l < E_){
    logits[t*E_+l] = acc[l];
    mask[t*E_+l] = (l==i1 || l==i2) ? 1 : 0;
  }
  if (l == 0){
    float inv = 1.f/s;
    top2[t*2] = i1; top2[t*2+1] = i2;
    p2[t*2] = p[i1]*inv; p2[t*2+1] = p[i2]*inv;
  }
}

// ---------------- capacity selection ----------------
__global__ __launch_bounds__(256) void k_capacity(const float* __restrict__ logits,
    const unsigned char* __restrict__ mask, const int* __restrict__ top2,
    int* __restrict__ kept, int* __restrict__ etok){
  int w = threadIdx.x >> 6, l = threadIdx.x & 63;
  int wid = blockIdx.x*4 + w;
  int t = wid >> 1, k = wid & 1;
  int e = top2[t*2+k];
  float my = logits[t*E_+e];
  int cnt = 0;
  for (int t2 = l; t2 < T_; t2 += 64){
    if (mask[t2*E_+e]){
      float lg = logits[t2*E_+e];
      if (lg > my || (lg == my && t2 < t)) cnt++;
    }
  }
  #pragma unroll
  for (int off=32; off; off>>=1) cnt += __shfl_xor(cnt, off, 64);
  if (l == 0){
    if (cnt < CAP_){ kept[t*2+k] = cnt; etok[e*CAP_+cnt] = t; }
    else kept[t*2+k] = -1;
  }
}

// ---------------- gather ----------------
template<bool SPLIT>
__global__ __launch_bounds__(256) void k_gather(const float* __restrict__ h,
    const int* __restrict__ etok, u16* __restrict__ xhi, u16* __restrict__ xlo){
  int rc = blockIdx.x;
  int tok = etok[rc];
  int d = threadIdx.x * 4;
  float4 v = make_float4(0.f,0.f,0.f,0.f);
  if (tok >= 0) v = *(const float4*)(h + (size_t)tok*D_ + d);
  union { u16 s[4]; uint2 u; } hi, lo;
  hi.s[0]=f2bf(v.x); lo.s[0]=f2bf(v.x - bf2f(hi.s[0]));
  hi.s[1]=f2bf(v.y); lo.s[1]=f2bf(v.y - bf2f(hi.s[1]));
  hi.s[2]=f2bf(v.z); lo.s[2]=f2bf(v.z - bf2f(hi.s[2]));
  hi.s[3]=f2bf(v.w); lo.s[3]=f2bf(v.w - bf2f(hi.s[3]));
  *(uint2*)(xhi + (size_t)rc*D_ + d) = hi.u;
  if (SPLIT) *(uint2*)(xlo + (size_t)rc*D_ + d) = lo.u;
}

// ---------------- expert GEMM v2 + vectorized (LDS-transposed) epilogue ----------------
template<bool SPLIT, bool GELU, int BN>
__global__ __launch_bounds__(512, 1) void k_expert(
    const u16* __restrict__ Ahi, const u16* __restrict__ Alo,
    const float* __restrict__ Bw,
    u16* __restrict__ Ohi, u16* __restrict__ Olo, float* __restrict__ Of,
    int N, int K){
  constexpr int NI = BN/64;
  constexpr int ABYTES = 2*16384*(SPLIT?2:1);
  constexpr int BSLOT = BN*80;
  constexpr int BBYTES = 2*BSLOT*(SPLIT?2:1);
  __shared__ __align__(16) char sm[ABYTES + BBYTES];
  char* smA   = sm;
  char* smALo = sm + 32768;
  char* smB   = sm + ABYTES;
  char* smBLo = sm + ABYTES + 2*BSLOT;

  int bid = blockIdx.x;
  int swz = (bid & 7)*32 + (bid >> 3);
  int e  = swz >> 4;
  int n0 = (swz & 15) * BN;
  int tid = threadIdx.x;
  int lane = tid & 63;
  int w = tid >> 6;
  int wm = w >> 2, wn = w & 3;
  int lr = lane & 15, lq = lane >> 4;
  int NK = K >> 5;

  const u16* Ah = Ahi + (size_t)e*256*K;
  const u16* Al = SPLIT ? (Alo + (size_t)e*256*K) : (const u16*)nullptr;
  const float* Bb = Bw + (size_t)e*K*N + n0;

  f32x4 acc[8][NI];
  #pragma unroll
  for (int i=0;i<8;++i)
    #pragma unroll
    for (int j=0;j<NI;++j)
      #pragma unroll
      for (int c=0;c<4;++c) acc[i][j][c] = 0.f;

  int t2 = tid - 256;
  const u16* aSrcH[4]; const u16* aSrcL[4]; int aDst[4];
  #pragma unroll
  for (int r=0;r<4;++r){
    int o = r*4096 + t2*16;
    int row = o >> 6;
    int cs = ((o >> 4) & 3) ^ ((row >> 1) & 3);
    aDst[r] = o;
    aSrcH[r] = Ah + (size_t)row*K + cs*8;
    if (SPLIT) aSrcL[r] = Al + (size_t)row*K + cs*8;
  }
  int kb = (BN==128) ? (tid>>5) : (tid>>4);
  int nb = (BN==128) ? (tid&31) : (tid&15);
  int wOff[4];
  #pragma unroll
  for (int j=0;j<4;++j){
    int n = nb*4 + j;
    int pos;
    if (BN==128) pos = ((kb ^ (2*(nb&3))) & 7) * 8;
    else         pos = (kb*4) ^ ((nb&3)*16);
    wOff[j] = n*80 + pos;
  }
  float4 pb[4];

  #define LOADPB_(k0n) do { \
    if constexpr (BN==128){ \
      const float* bp = Bb + (size_t)((k0n) + kb*4)*N + nb*4; \
      pb[0] = *(const float4*)bp; pb[1] = *(const float4*)(bp + N); \
      pb[2] = *(const float4*)(bp + 2*N); pb[3] = *(const float4*)(bp + 3*N); \
    } else { \
      const float* bp = Bb + (size_t)((k0n) + kb*2)*N + nb*4; \
      pb[0] = *(const float4*)bp; pb[1] = *(const float4*)(bp + N); \
    } } while(0)

  #define WRITEB_(slot) do { \
    char* bh_ = smB + (slot)*BSLOT; char* bl_ = smBLo + (slot)*BSLOT; \
    if constexpr (BN==128){ \
      float cv[4][4] = {{pb[0].x,pb[1].x,pb[2].x,pb[3].x},{pb[0].y,pb[1].y,pb[2].y,pb[3].y}, \
                        {pb[0].z,pb[1].z,pb[2].z,pb[3].z},{pb[0].w,pb[1].w,pb[2].w,pb[3].w}}; \
      _Pragma("unroll") for (int j=0;j<4;++j){ \
        union { u16 s[4]; uint2 u; } hi, lo; \
        _Pragma("unroll") for (int i=0;i<4;++i){ \
          hi.s[i] = f2bf(cv[j][i]); \
          if constexpr (SPLIT) lo.s[i] = f2bf(cv[j][i] - bf2f(hi.s[i])); } \
        *(uint2*)(bh_ + wOff[j]) = hi.u; \
        if constexpr (SPLIT) *(uint2*)(bl_ + wOff[j]) = lo.u; } \
    } else { \
      float cv[4][2] = {{pb[0].x,pb[1].x},{pb[0].y,pb[1].y},{pb[0].z,pb[1].z},{pb[0].w,pb[1].w}}; \
      _Pragma("unroll") for (int j=0;j<4;++j){ \
        union { u16 s[2]; u32 u; } hi, lo; \
        _Pragma("unroll") for (int i=0;i<2;++i){ \
          hi.s[i] = f2bf(cv[j][i]); \
          if constexpr (SPLIT) lo.s[i] = f2bf(cv[j][i] - bf2f(hi.s[i])); } \
        *(u32*)(bh_ + wOff[j]) = hi.u; \
        if constexpr (SPLIT) *(u32*)(bl_ + wOff[j]) = lo.u; } \
    } } while(0)

  #define STAGEA_(k0n, slot) do { \
    _Pragma("unroll") for (int r=0;r<4;++r){ \
      gl_lds16(aSrcH[r] + (k0n), smA + (slot)*16384 + aDst[r]); \
      if constexpr (SPLIT) gl_lds16(aSrcL[r] + (k0n), smALo + (slot)*16384 + aDst[r]); \
    } } while(0)

  if (tid < 256){
    LOADPB_(0);
    WRITEB_(0);
    if (NK > 1) LOADPB_(32);
  } else {
    STAGEA_(0, 0);
  }
  __syncthreads();

  int aRo[8];
  #pragma unroll
  for (int mi=0;mi<8;++mi){
    int row = wm*128 + mi*16 + lr;
    aRo[mi] = row*64 + ((lq ^ ((row>>1)&3))<<4);
  }
  int bRo[NI];
  #pragma unroll
  for (int ni=0;ni<NI;++ni){
    int n = wn*(BN/4) + ni*16 + lr;
    bRo[ni] = n*80 + ((lq ^ ((n>>2)&3))<<4);
  }

  for (int ks = 0; ks < NK; ++ks){
    int cur = ks & 1;
    bf16x8 bh[NI], bl[NI];
    #pragma unroll
    for (int ni=0;ni<NI;++ni){
      bh[ni] = *(const bf16x8*)(smB + cur*BSLOT + bRo[ni]);
      if constexpr (SPLIT) bl[ni] = *(const bf16x8*)(smBLo + cur*BSLOT + bRo[ni]);
    }
    if (ks + 1 < NK){
      int nslot = cur ^ 1;
      if (tid < 256){
        WRITEB_(nslot);
        if (ks + 2 < NK) LOADPB_((ks+2)*32);
      } else {
        STAGEA_((ks+1)*32, nslot);
      }
    }
    #pragma unroll
    for (int mi=0;mi<8;++mi){
      bf16x8 ah = *(const bf16x8*)(smA + cur*16384 + aRo[mi]);
      if constexpr (SPLIT){
        bf16x8 al = *(const bf16x8*)(smALo + cur*16384 + aRo[mi]);
        #pragma unroll
        for (int ni=0;ni<NI;++ni){
          acc[mi][ni] = mfma16(ah, bh[ni], acc[mi][ni]);
          acc[mi][ni] = mfma16(al, bh[ni], acc[mi][ni]);
          acc[mi][ni] = mfma16(ah, bl[ni], acc[mi][ni]);
        }
      } else {
        #pragma unroll
        for (int ni=0;ni<NI;++ni)
          acc[mi][ni] = mfma16(ah, bh[ni], acc[mi][ni]);
      }
    }
    __syncthreads();
  }
  #undef LOADPB_
  #undef WRITEB_
  #undef STAGEA_

  // ---- epilogue: per-wave LDS transpose -> vectorized stores ----
  {
    constexpr int STRIPB = NI*16*4*16;
    char* strip = sm + w*STRIPB;
    int r = lane & 15;
    int b = lane >> 4;
    #pragma unroll
    for (int mi=0;mi<8;++mi){
      #pragma unroll
      for (int ni=0;ni<NI;++ni){
        int col = ni*16 + lr;
        f32x4 v = acc[mi][ni];
        if constexpr (GELU){
          v[0]=gelu_tanh(v[0]); v[1]=gelu_tanh(v[1]);
          v[2]=gelu_tanh(v[2]); v[3]=gelu_tanh(v[3]);
        }
        *(f32x4*)(strip + (col*4 + lq)*16) = v;
      }
      asm volatile("s_waitcnt lgkmcnt(0)" ::: "memory");
      __builtin_amdgcn_sched_barrier(0);
      int grow = wm*128 + mi*16 + r;
      if constexpr (GELU){
        union { u16 s[8]; uint4 v; } ph, pl;
        #pragma unroll
        for (int i=0;i<8;++i){
          float y = *(const float*)(strip + ((b*8+i)*4 + (r>>2))*16 + (r&3)*4);
          ph.s[i] = f2bf(y);
          if constexpr (SPLIT) pl.s[i] = f2bf(y - bf2f(ph.s[i]));
        }
        size_t idx = ((size_t)e*256 + grow)*N + n0 + wn*(BN/4) + b*8;
        *(uint4*)(Ohi + idx) = ph.v;
        if constexpr (SPLIT) *(uint4*)(Olo + idx) = pl.v;
      } else {
        #pragma unroll
        for (int cc=0; cc<NI; ++cc){
          int c = b + cc*4;
          float4 o;
          o.x = *(const float*)(strip + ((c*4+0)*4 + (r>>2))*16 + (r&3)*4);
          o.y = *(const float*)(strip + ((c*4+1)*4 + (r>>2))*16 + (r&3)*4);
          o.z = *(const float*)(strip + ((c*4+2)*4 + (r>>2))*16 + (r&3)*4);
          o.w = *(const float*)(strip + ((c*4+3)*4 + (r>>2))*16 + (r&3)*4);
          *(float4*)(Of + ((size_t)e*256 + grow)*N + n0 + wn*(BN/4) + c*4) = o;
        }
      }
      asm volatile("s_waitcnt lgkmcnt(0)" ::: "memory");
    }
  }
}

// ---------------- combine (optionally fused RMSNorm -> bf16) ----------------
template<bool FINAL>
__global__ __launch_bounds__(256) void k_combine(float* __restrict__ h,
    const float* __restrict__ Y2, const int* __restrict__ top2,
    const float* __restrict__ p2, const int* __restrict__ kept,
    const float* __restrict__ g, u16* __restrict__ hn){
  int t = blockIdx.x;
  int e0 = top2[t*2], e1 = top2[t*2+1];
  int r0 = kept[t*2], r1 = kept[t*2+1];
  float w0 = (r0 >= 0) ? p2[t*2]   : 0.f;
  float w1 = (r1 >= 0) ? p2[t*2+1] : 0.f;
  float om = 1.f - w0 - w1;
  int d = threadIdx.x * 4;
  float4 v = *(const float4*)(h + (size_t)t*D_ + d);
  float ox = v.x*om, oy = v.y*om, oz = v.z*om, ow = v.w*om;
  if (r0 >= 0){
    float4 y = *(const float4*)(Y2 + ((size_t)e0*CAP_ + r0)*D_ + d);
    ox += w0*y.x; oy += w0*y.y; oz += w0*y.z; ow += w0*y.w;
  }
  if (r1 >= 0){
    float4 y = *(const float4*)(Y2 + ((size_t)e1*CAP_ + r1)*D_ + d);
    ox += w1*y.x; oy += w1*y.y; oz += w1*y.z; ow += w1*y.w;
  }
  if constexpr (!FINAL){
    *(float4*)(h + (size_t)t*D_ + d) = make_float4(ox, oy, oz, ow);
  } else {
    int w = threadIdx.x >> 6, l = threadIdx.x & 63;
    __shared__ float red[4];
    float ss = ox*ox + oy*oy + oz*oz + ow*ow;
    #pragma unroll
    for (int off=32; off; off>>=1) ss += __shfl_xor(ss, off, 64);
    if (l == 0) red[w] = ss;
    __syncthreads();
    float tot = red[0] + red[1] + red[2] + red[3];
    float sc = rsqrtf(tot * (1.f/D_) + 1e-5f);
    float4 gs = *(const float4*)(g + d);
    union { u16 s[4]; uint2 u; } o;
    o.s[0] = f2bf(ox*sc*gs.x); o.s[1] = f2bf(oy*sc*gs.y);
    o.s[2] = f2bf(oz*sc*gs.z); o.s[3] = f2bf(ow*sc*gs.w);
    *(uint2*)(hn + (size_t)t*D_ + d) = o.u;
  }
}

// ---------------- final GEMM v7: 256x256, 4-slot ring, reg-dbuf frags.
// Change vs R6: NO sched_barrier(0) pins (m141 trap) — compiler free to
// interleave MFMA with waits/reads using its own fine-grained lgkmcnt;
// asm "memory" clobbers alone enforce the cross-wave hazards:
//   vmcnt(8) pre-barrier => slot kh+1 globally staged before READF(kh+1);
//   lgkmcnt(0) pre-barrier => slot kh-1 reads drained before its overwrite.
// Epilogue: LDS-transpose + nontemporal float4 stores (don't pollute L2/L3).
#define SLOT_ 16384
__global__ __launch_bounds__(512, 2) void k_gemm_final(const u16* __restrict__ A,
    const u16* __restrict__ B, float* __restrict__ C){
  __shared__ __align__(16) char lds[131072];
  char* ldsA = lds;
  char* ldsB = lds + 65536;
  int bid = blockIdx.x;
  int wgid = (bid & 7) * 125 + (bid >> 3);   // bijective: 1000 = 8*125
  int m0 = (wgid & 7) << 8;
  int n0 = (wgid >> 3) << 8;
  int tid = threadIdx.x;
  int lane = tid & 63;
  int w = tid >> 6;
  int wm = w >> 2, wn = w & 3;
  int lr = lane & 15, lq = lane >> 4;

  f32x4 acc[8][4];
  #pragma unroll
  for (int i=0;i<8;++i)
    #pragma unroll
    for (int j=0;j<4;++j)
      #pragma unroll
      for (int c=0;c<4;++c) acc[i][j][c] = 0.f;

  int j_0 = w*2, j_1 = w*2 + 1;
  int rp0 = j_0*8 + (lane>>3), rp1 = j_1*8 + (lane>>3);
  int c80 = (lane&7) ^ (rp0&7), c81 = (lane&7) ^ (rp1&7);
  int rA0 = rp0*2 + (c80>>2), rA1 = rp1*2 + (c81>>2);
  int cc0 = (c80&3)*8,        cc1 = (c81&3)*8;
  const u16* sA0 = A + (size_t)(m0+rA0)*D_ + cc0;
  const u16* sA1 = A + (size_t)(m0+rA1)*D_ + cc1;
  const u16* sB0 = B + (size_t)(n0+rA0)*D_ + cc0;
  const u16* sB1 = B + (size_t)(n0+rA1)*D_ + cc1;
  int d0 = j_0*1024 + lane*16, d1 = j_1*1024 + lane*16;

  int aoff[8], boff[4];
  #pragma unroll
  for (int mi=0;mi<8;++mi){
    int r = wm*128 + mi*16 + lr;
    int rp = r >> 1;
    int c8 = ((r&1)<<2) | lq;
    aoff[mi] = rp*128 + ((c8 ^ (rp&7))<<4);
  }
  #pragma unroll
  for (int ni=0;ni<4;++ni){
    int r = wn*64 + ni*16 + lr;
    int rp = r >> 1;
    int c8 = ((r&1)<<2) | lq;
    boff[ni] = rp*128 + ((c8 ^ (rp&7))<<4);
  }

  #define STAGE_(sbase) do { \
    gl_lds16(sA0, ldsA + (sbase) + d0); gl_lds16(sB0, ldsB + (sbase) + d0); \
    gl_lds16(sA1, ldsA + (sbase) + d1); gl_lds16(sB1, ldsB + (sbase) + d1); \
    sA0 += 32; sA1 += 32; sB0 += 32; sB1 += 32; } while(0)

  bf16x8 aF0[8], bF0[4], aF1[8], bF1[4];

  STAGE_(0); STAGE_(SLOT_); STAGE_(2*SLOT_);
  asm volatile("s_waitcnt vmcnt(8)" ::: "memory");
  __builtin_amdgcn_s_barrier();
  {
    const char* pA_ = ldsA; const char* pB_ = ldsB;
    #pragma unroll
    for (int ni=0;ni<4;++ni) bF0[ni] = *(const bf16x8*)(pB_ + boff[ni]);
    #pragma unroll
    for (int mi=0;mi<8;++mi) aF0[mi] = *(const bf16x8*)(pA_ + aoff[mi]);
  }

  #define PHASE_(kh, FAc, FBc, FAn, FBn) do { \
    if ((kh) <= 28) STAGE_((((kh)+3)&3)*SLOT_); \
    if ((kh) <= 28)      asm volatile("s_waitcnt vmcnt(8)" ::: "memory"); \
    else if ((kh) == 29) asm volatile("s_waitcnt vmcnt(4)" ::: "memory"); \
    else if ((kh) == 30) asm volatile("s_waitcnt vmcnt(0)" ::: "memory"); \
    asm volatile("s_waitcnt lgkmcnt(0)" ::: "memory"); \
    __builtin_amdgcn_s_barrier(); \
    if ((kh) < 31){ \
      int sb_ = (((kh)+1)&3)*SLOT_; \
      const char* pA_ = ldsA + sb_; const char* pB_ = ldsB + sb_; \
      _Pragma("unroll") for (int ni=0;ni<4;++ni) FBn[ni] = *(const bf16x8*)(pB_ + boff[ni]); \
      _Pragma("unroll") for (int mi=0;mi<8;++mi) FAn[mi] = *(const bf16x8*)(pA_ + aoff[mi]); \
    } \
    __builtin_amdgcn_s_setprio(1); \
    _Pragma("unroll") for (int mi=0;mi<8;++mi){ \
      _Pragma("unroll") for (int ni=0;ni<4;++ni) \
        acc[mi][ni] = mfma16(FAc[mi], FBc[ni], acc[mi][ni]); \
    } \
    __builtin_amdgcn_s_setprio(0); \
  } while(0)

  for (int kh2 = 0; kh2 < 32; kh2 += 2){
    PHASE_(kh2,     aF0, bF0, aF1, bF1);
    PHASE_(kh2 + 1, aF1, bF1, aF0, bF0);
  }
  #undef PHASE_
  #undef STAGE_

  // ---- epilogue: per-wave 4 KB strip; nontemporal float4 stores ----
  {
    char* strip = lds + w*4096;
    int r = lane & 15;
    int b = lane >> 4;
    #pragma unroll
    for (int mi=0;mi<8;++mi){
      #pragma unroll
      for (int ni=0;ni<4;++ni){
        int col = ni*16 + lr;
        *(f32x4*)(strip + (col*4 + lq)*16) = acc[mi][ni];
      }
      asm volatile("s_waitcnt lgkmcnt(0)" ::: "memory");
      __builtin_amdgcn_sched_barrier(0);
      int grow = m0 + wm*128 + mi*16 + r;
      #pragma unroll
      for (int cc=0; cc<4; ++cc){
        int c = b + cc*4;
        f32x4 o;
        o[0] = *(const float*)(strip + ((c*4+0)*4 + (r>>2))*16 + (r&3)*4);
        o[1] = *(const float*)(strip + ((c*4+1)*4 + (r>>2))*16 + (r&3)*4);
        o[2] = *(const float*)(strip + ((c*4+2)*4 + (r>>2))*16 + (r&3)*4);
        o[3] = *(const float*)(strip + ((c*4+3)*4 + (r>>2))*16 + (r&3)*4);
        nt_store4(&C[(size_t)grow*V_ + n0 + wn*64 + c*4], o);
      }
      asm volatile("s_waitcnt lgkmcnt(0)" ::: "memory");
    }
  }
}

extern "C" void kernel_launch(void* const* d_in, const int* in_sizes, int n_in,
                              void* d_out, int out_size, void* d_ws, size_t ws_size,
                              hipStream_t stream){
  const int*   ids  = (const int*)d_in[0];
  const float* embW = (const float*)d_in[1];
  const float* lns  = (const float*)d_in[2];
  const float* WrA  = (const float*)d_in[3];
  const float* W1A  = (const float*)d_in[4];
  const float* W2A  = (const float*)d_in[5];
  float* out = (float*)d_out;
  char* ws = (char*)d_ws;
  const size_t MB = 1u << 20;

  float* h      = (float*)(ws);
  float* logits = (float*)(ws + 8*MB);
  unsigned char* mask = (unsigned char*)(ws + 8*MB + 131072);
  int*   top2v  = (int*)(ws + 8*MB + 131072 + 32768);
  float* p2     = (float*)(ws + 8*MB + 131072 + 32768 + 16384);
  int*   kept   = (int*)(ws + 8*MB + 131072 + 32768 + 32768);
  int*   etok   = (int*)(ws + 8*MB + 131072 + 32768 + 49152);
  u16*   xhi  = (u16*)(ws + 9*MB);
  u16*   xlo  = (u16*)(ws + 17*MB);
  float* y2   = (float*)(ws + 9*MB);            // aliases xhi/xlo (dead by then)
  u16*   y1hi = (u16*)(ws + 25*MB);
  u16*   y1lo = (u16*)(ws + 41*MB);
  u16*   hn   = (u16*)(ws + 57*MB);
  u16*   ebf  = (u16*)(ws + 61*MB);

  k_cvtw<<<(V_*D_)/(256*8), 256, 0, stream>>>(embW, ebf);

  for (int hop = 0; hop < 2; ++hop){
    const float* Wr = WrA + (size_t)hop*D_*E_;
    const float* W1 = W1A + (size_t)hop*E_*D_*DFF_;
    const float* W2 = W2A + (size_t)hop*E_*DFF_*D_;
    if (hop == 0){
      k_router<true ><<<T_/4, 256, 0, stream>>>(h, Wr, logits, mask, top2v, p2, ids, embW, etok);
      k_capacity<<<T_*2/4, 256, 0, stream>>>(logits, mask, top2v, kept, etok);
      k_gather<true ><<<E_*CAP_, 256, 0, stream>>>(h, etok, xhi, xlo);
      k_expert<true , true , 128><<<E_*(DFF_/128), 512, 0, stream>>>(
          xhi, xlo, W1, y1hi, y1lo, nullptr, DFF_, D_);
      k_expert<true , false, 64 ><<<E_*(D_/64), 512, 0, stream>>>(
          y1hi, y1lo, W2, nullptr, nullptr, y2, D_, DFF_);
      k_combine<false><<<T_, 256, 0, stream>>>(h, y2, top2v, p2, kept, lns, hn);
    } else {
      k_router<false><<<T_/4, 256, 0, stream>>>(h, Wr, logits, mask, top2v, p2, ids, embW, etok);
      k_capacity<<<T_*2/4, 256, 0, stream>>>(logits, mask, top2v, kept, etok);
      k_gather<false><<<E_*CAP_, 256, 0, stream>>>(h, etok, xhi, xlo);
      k_expert<false, true , 128><<<E_*(DFF_/128), 512, 0, stream>>>(
          xhi, nullptr, W1, y1hi, nullptr, nullptr, DFF_, D_);
      k_expert<false, false, 64 ><<<E_*(D_/64), 512, 0, stream>>>(
          y1hi, nullptr, W2, nullptr, nullptr, y2, D_, DFF_);
      k_combine<true ><<<T_, 256, 0, stream>>>(h, y2, top2v, p2, kept, lns, hn);
    }
  }

  k_gemm_final<<<(T_/256)*(V_/256), 512, 0, stream>>>(hn, ebf, out);
}

// Round 10
// 548.918 us; speedup vs baseline: 1.2581x; 1.1693x over previous
//
#include <hip/hip_runtime.h>
#include <stdint.h>

#define T_ 2048
#define V_ 32000
#define D_ 1024
#define E_ 16
#define CAP_ 256
#define DFF_ 2048

typedef unsigned short u16;
typedef unsigned int u32;
typedef __bf16 bf16x8 __attribute__((ext_vector_type(8)));
typedef float f32x4 __attribute__((ext_vector_type(4)));

__device__ __forceinline__ u16 f2bf(float f){
  u32 u = __float_as_uint(f);
  u32 r = u + 0x7FFFu + ((u >> 16) & 1u);
  return (u16)(r >> 16);
}
__device__ __forceinline__ float bf2f(u16 s){ return __uint_as_float(((u32)s) << 16); }

__device__ __forceinline__ void gl_lds16(const void* g, void* l){
  __builtin_amdgcn_global_load_lds((const __attribute__((address_space(1))) void*)g,
                                   (__attribute__((address_space(3))) void*)l, 16, 0, 0);
}
__device__ __forceinline__ f32x4 mfma16(bf16x8 a, bf16x8 b, f32x4 c){
  return __builtin_amdgcn_mfma_f32_16x16x32_bf16(a, b, c, 0, 0, 0);
}
__device__ __forceinline__ float gelu_tanh(float x){
  float u = 0.7978845608028654f * (x + 0.044715f * x * x * x);
  return 0.5f * x * (1.0f + tanhf(u));
}

// ---------------- embed_W fp32 -> bf16 ----------------
__global__ __launch_bounds__(256) void k_cvtw(const float* __restrict__ W, u16* __restrict__ Wb){
  size_t i = ((size_t)blockIdx.x*256 + threadIdx.x)*8;
  float4 a = *(const float4*)(W + i);
  float4 b = *(const float4*)(W + i + 4);
  union { u16 s[8]; uint4 v; } p;
  p.s[0]=f2bf(a.x); p.s[1]=f2bf(a.y); p.s[2]=f2bf(a.z); p.s[3]=f2bf(a.w);
  p.s[4]=f2bf(b.x); p.s[5]=f2bf(b.y); p.s[6]=f2bf(b.z); p.s[7]=f2bf(b.w);
  *(uint4*)(Wb + i) = p.v;
}

// ---------------- router (+etok init; optionally fused embedding) ----------------
template<bool EMB>
__global__ __launch_bounds__(256) void k_router(float* __restrict__ h,
    const float* __restrict__ Wr, float* __restrict__ logits,
    unsigned char* __restrict__ mask, int* __restrict__ top2, float* __restrict__ p2,
    const int* __restrict__ ids, const float* __restrict__ embW, int* __restrict__ etok){
  if (blockIdx.x < (E_*CAP_)/256) etok[blockIdx.x*256 + threadIdx.x] = -1;
  int w = threadIdx.x >> 6, l = threadIdx.x & 63;
  int t = blockIdx.x*4 + w;
  float acc[E_];
  #pragma unroll
  for (int e=0;e<E_;++e) acc[e]=0.f;
  const float* hrow = EMB ? (embW + (size_t)ids[t]*D_) : (h + (size_t)t*D_);
  #pragma unroll
  for (int i=0;i<16;++i){
    int d = l + i*64;
    float hv = hrow[d];
    if (EMB) h[(size_t)t*D_ + d] = hv;
    const float4* wr = (const float4*)(Wr + d*E_);
    float4 w0=wr[0], w1=wr[1], w2=wr[2], w3=wr[3];
    acc[0]+=hv*w0.x; acc[1]+=hv*w0.y; acc[2]+=hv*w0.z; acc[3]+=hv*w0.w;
    acc[4]+=hv*w1.x; acc[5]+=hv*w1.y; acc[6]+=hv*w1.z; acc[7]+=hv*w1.w;
    acc[8]+=hv*w2.x; acc[9]+=hv*w2.y; acc[10]+=hv*w2.z; acc[11]+=hv*w2.w;
    acc[12]+=hv*w3.x; acc[13]+=hv*w3.y; acc[14]+=hv*w3.z; acc[15]+=hv*w3.w;
  }
  #pragma unroll
  for (int off=32; off; off>>=1){
    #pragma unroll
    for (int e=0;e<E_;++e) acc[e] += __shfl_xor(acc[e], off, 64);
  }
  float mx = acc[0];
  #pragma unroll
  for (int e=1;e<E_;++e) mx = fmaxf(mx, acc[e]);
  float p[E_], s = 0.f;
  #pragma unroll
  for (int e=0;e<E_;++e){ p[e] = expf(acc[e]-mx); s += p[e]; }
  int i1 = 0; float v1 = acc[0];
  #pragma unroll
  for (int e=1;e<E_;++e) if (acc[e] > v1){ v1 = acc[e]; i1 = e; }
  int i2 = (i1==0)?1:0; float v2 = acc[i2];
  #pragma unroll
  for (int e=0;e<E_;++e) if (e!=i1 && e!=i2 && acc[e] > v2){ v2 = acc[e]; i2 = e; }
  if (l < E_){
    logits[t*E_+l] = acc[l];
    mask[t*E_+l] = (l==i1 || l==i2) ? 1 : 0;
  }
  if (l == 0){
    float inv = 1.f/s;
    top2[t*2] = i1; top2[t*2+1] = i2;
    p2[t*2] = p[i1]*inv; p2[t*2+1] = p[i2]*inv;
  }
}

// ---------------- capacity selection ----------------
__global__ __launch_bounds__(256) void k_capacity(const float* __restrict__ logits,
    const unsigned char* __restrict__ mask, const int* __restrict__ top2,
    int* __restrict__ kept, int* __restrict__ etok){
  int w = threadIdx.x >> 6, l = threadIdx.x & 63;
  int wid = blockIdx.x*4 + w;
  int t = wid >> 1, k = wid & 1;
  int e = top2[t*2+k];
  float my = logits[t*E_+e];
  int cnt = 0;
  for (int t2 = l; t2 < T_; t2 += 64){
    if (mask[t2*E_+e]){
      float lg = logits[t2*E_+e];
      if (lg > my || (lg == my && t2 < t)) cnt++;
    }
  }
  #pragma unroll
  for (int off=32; off; off>>=1) cnt += __shfl_xor(cnt, off, 64);
  if (l == 0){
    if (cnt < CAP_){ kept[t*2+k] = cnt; etok[e*CAP_+cnt] = t; }
    else kept[t*2+k] = -1;
  }
}

// ---------------- gather ----------------
template<bool SPLIT>
__global__ __launch_bounds__(256) void k_gather(const float* __restrict__ h,
    const int* __restrict__ etok, u16* __restrict__ xhi, u16* __restrict__ xlo){
  int rc = blockIdx.x;
  int tok = etok[rc];
  int d = threadIdx.x * 4;
  float4 v = make_float4(0.f,0.f,0.f,0.f);
  if (tok >= 0) v = *(const float4*)(h + (size_t)tok*D_ + d);
  union { u16 s[4]; uint2 u; } hi, lo;
  hi.s[0]=f2bf(v.x); lo.s[0]=f2bf(v.x - bf2f(hi.s[0]));
  hi.s[1]=f2bf(v.y); lo.s[1]=f2bf(v.y - bf2f(hi.s[1]));
  hi.s[2]=f2bf(v.z); lo.s[2]=f2bf(v.z - bf2f(hi.s[2]));
  hi.s[3]=f2bf(v.w); lo.s[3]=f2bf(v.w - bf2f(hi.s[3]));
  *(uint2*)(xhi + (size_t)rc*D_ + d) = hi.u;
  if (SPLIT) *(uint2*)(xlo + (size_t)rc*D_ + d) = lo.u;
}

// ---------------- expert GEMM v3: BM=128 (half expert), 2-3 blocks/CU ----------------
// Same proven staging/phase structure as v2, but half-height A tile cuts LDS
// (SPLIT-W1 106->72 KB) so 2+ blocks co-reside per CU and overlap each other's
// barrier stalls. __launch_bounds__(512,4) caps VGPR at 128 to allow it.
template<bool SPLIT, bool GELU, int BN>
__global__ __launch_bounds__(512, 4) void k_expert(
    const u16* __restrict__ Ahi, const u16* __restrict__ Alo,
    const float* __restrict__ Bw,
    u16* __restrict__ Ohi, u16* __restrict__ Olo, float* __restrict__ Of,
    int N, int K){
  constexpr int NI = BN/64;
  constexpr int ASLOT = 8192;                  // 128 rows x 32 cols x 2B
  constexpr int ABYTES = 2*ASLOT*(SPLIT?2:1);
  constexpr int BSLOT = BN*80;
  constexpr int BBYTES = 2*BSLOT*(SPLIT?2:1);
  __shared__ __align__(16) char sm[ABYTES + BBYTES];
  char* smA   = sm;
  char* smALo = sm + 2*ASLOT;
  char* smB   = sm + ABYTES;
  char* smBLo = sm + ABYTES + 2*BSLOT;

  int bid = blockIdx.x;
  int swz = (bid & 7)*64 + (bid >> 3);         // grid 512 = 8*64, XCD-contig
  int e   = swz >> 5;                          // 32 tiles per expert
  int rem = swz & 31;
  int mt  = rem & 1;
  int nt  = rem >> 1;
  int n0  = nt * BN;
  int tid = threadIdx.x;
  int lane = tid & 63;
  int w = tid >> 6;
  int wm = w >> 2, wn = w & 3;                 // 2m x 4n, wave tile 64 x BN/4
  int lr = lane & 15, lq = lane >> 4;
  int NK = K >> 5;

  const u16* Ah = Ahi + ((size_t)e*256 + mt*128)*K;
  const u16* Al = SPLIT ? (Alo + ((size_t)e*256 + mt*128)*K) : (const u16*)nullptr;
  const float* Bb = Bw + (size_t)e*K*N + n0;

  f32x4 acc[4][NI];
  #pragma unroll
  for (int i=0;i<4;++i)
    #pragma unroll
    for (int j=0;j<NI;++j)
      #pragma unroll
      for (int c=0;c<4;++c) acc[i][j][c] = 0.f;

  // waves 4-7: A staging (2 x 4096B gl_lds per thread-group slice)
  int t2 = tid - 256;
  const u16* aSrcH[2]; const u16* aSrcL[2]; int aDst[2];
  #pragma unroll
  for (int r=0;r<2;++r){
    int o = r*4096 + t2*16;
    int row = o >> 6;
    int cs = ((o >> 4) & 3) ^ ((row >> 1) & 3);
    aDst[r] = o;
    aSrcH[r] = Ah + (size_t)row*K + cs*8;
    if (SPLIT) aSrcL[r] = Al + (size_t)row*K + cs*8;
  }
  // waves 0-3: B tile 32xBN fp32 -> regs -> bf16 hi/lo ds_write
  int kb = (BN==128) ? (tid>>5) : (tid>>4);
  int nb = (BN==128) ? (tid&31) : (tid&15);
  int wOff[4];
  #pragma unroll
  for (int j=0;j<4;++j){
    int n = nb*4 + j;
    int pos;
    if (BN==128) pos = ((kb ^ (2*(nb&3))) & 7) * 8;
    else         pos = (kb*4) ^ ((nb&3)*16);
    wOff[j] = n*80 + pos;
  }
  float4 pb[4];

  #define LOADPB_(k0n) do { \
    if constexpr (BN==128){ \
      const float* bp = Bb + (size_t)((k0n) + kb*4)*N + nb*4; \
      pb[0] = *(const float4*)bp; pb[1] = *(const float4*)(bp + N); \
      pb[2] = *(const float4*)(bp + 2*N); pb[3] = *(const float4*)(bp + 3*N); \
    } else { \
      const float* bp = Bb + (size_t)((k0n) + kb*2)*N + nb*4; \
      pb[0] = *(const float4*)bp; pb[1] = *(const float4*)(bp + N); \
    } } while(0)

  #define WRITEB_(slot) do { \
    char* bh_ = smB + (slot)*BSLOT; char* bl_ = smBLo + (slot)*BSLOT; \
    if constexpr (BN==128){ \
      float cv[4][4] = {{pb[0].x,pb[1].x,pb[2].x,pb[3].x},{pb[0].y,pb[1].y,pb[2].y,pb[3].y}, \
                        {pb[0].z,pb[1].z,pb[2].z,pb[3].z},{pb[0].w,pb[1].w,pb[2].w,pb[3].w}}; \
      _Pragma("unroll") for (int j=0;j<4;++j){ \
        union { u16 s[4]; uint2 u; } hi, lo; \
        _Pragma("unroll") for (int i=0;i<4;++i){ \
          hi.s[i] = f2bf(cv[j][i]); \
          if constexpr (SPLIT) lo.s[i] = f2bf(cv[j][i] - bf2f(hi.s[i])); } \
        *(uint2*)(bh_ + wOff[j]) = hi.u; \
        if constexpr (SPLIT) *(uint2*)(bl_ + wOff[j]) = lo.u; } \
    } else { \
      float cv[4][2] = {{pb[0].x,pb[1].x},{pb[0].y,pb[1].y},{pb[0].z,pb[1].z},{pb[0].w,pb[1].w}}; \
      _Pragma("unroll") for (int j=0;j<4;++j){ \
        union { u16 s[2]; u32 u; } hi, lo; \
        _Pragma("unroll") for (int i=0;i<2;++i){ \
          hi.s[i] = f2bf(cv[j][i]); \
          if constexpr (SPLIT) lo.s[i] = f2bf(cv[j][i] - bf2f(hi.s[i])); } \
        *(u32*)(bh_ + wOff[j]) = hi.u; \
        if constexpr (SPLIT) *(u32*)(bl_ + wOff[j]) = lo.u; } \
    } } while(0)

  #define STAGEA_(k0n, slot) do { \
    _Pragma("unroll") for (int r=0;r<2;++r){ \
      gl_lds16(aSrcH[r] + (k0n), smA + (slot)*ASLOT + aDst[r]); \
      if constexpr (SPLIT) gl_lds16(aSrcL[r] + (k0n), smALo + (slot)*ASLOT + aDst[r]); \
    } } while(0)

  if (tid < 256){
    LOADPB_(0);
    WRITEB_(0);
    if (NK > 1) LOADPB_(32);
  } else {
    STAGEA_(0, 0);
  }
  __syncthreads();

  int aRo[4];
  #pragma unroll
  for (int mi=0;mi<4;++mi){
    int row = wm*64 + mi*16 + lr;
    aRo[mi] = row*64 + ((lq ^ ((row>>1)&3))<<4);
  }
  int bRo[NI];
  #pragma unroll
  for (int ni=0;ni<NI;++ni){
    int n = wn*(BN/4) + ni*16 + lr;
    bRo[ni] = n*80 + ((lq ^ ((n>>2)&3))<<4);
  }

  for (int ks = 0; ks < NK; ++ks){
    int cur = ks & 1;
    bf16x8 bh[NI], bl[NI];
    #pragma unroll
    for (int ni=0;ni<NI;++ni){
      bh[ni] = *(const bf16x8*)(smB + cur*BSLOT + bRo[ni]);
      if constexpr (SPLIT) bl[ni] = *(const bf16x8*)(smBLo + cur*BSLOT + bRo[ni]);
    }
    if (ks + 1 < NK){
      int nslot = cur ^ 1;
      if (tid < 256){
        WRITEB_(nslot);
        if (ks + 2 < NK) LOADPB_((ks+2)*32);
      } else {
        STAGEA_((ks+1)*32, nslot);
      }
    }
    #pragma unroll
    for (int mi=0;mi<4;++mi){
      bf16x8 ah = *(const bf16x8*)(smA + cur*ASLOT + aRo[mi]);
      if constexpr (SPLIT){
        bf16x8 al = *(const bf16x8*)(smALo + cur*ASLOT + aRo[mi]);
        #pragma unroll
        for (int ni=0;ni<NI;++ni){
          acc[mi][ni] = mfma16(ah, bh[ni], acc[mi][ni]);
          acc[mi][ni] = mfma16(al, bh[ni], acc[mi][ni]);
          acc[mi][ni] = mfma16(ah, bl[ni], acc[mi][ni]);
        }
      } else {
        #pragma unroll
        for (int ni=0;ni<NI;++ni)
          acc[mi][ni] = mfma16(ah, bh[ni], acc[mi][ni]);
      }
    }
    __syncthreads();
  }
  #undef LOADPB_
  #undef WRITEB_
  #undef STAGEA_

  // ---- epilogue: per-wave LDS transpose -> vectorized stores ----
  {
    constexpr int STRIPB = NI*16*4*16;
    char* strip = sm + w*STRIPB;
    int r = lane & 15;
    int b = lane >> 4;
    #pragma unroll
    for (int mi=0;mi<4;++mi){
      #pragma unroll
      for (int ni=0;ni<NI;++ni){
        int col = ni*16 + lr;
        f32x4 v = acc[mi][ni];
        if constexpr (GELU){
          v[0]=gelu_tanh(v[0]); v[1]=gelu_tanh(v[1]);
          v[2]=gelu_tanh(v[2]); v[3]=gelu_tanh(v[3]);
        }
        *(f32x4*)(strip + (col*4 + lq)*16) = v;
      }
      asm volatile("s_waitcnt lgkmcnt(0)" ::: "memory");
      __builtin_amdgcn_sched_barrier(0);
      int grow = mt*128 + wm*64 + mi*16 + r;
      if constexpr (GELU){
        union { u16 s[8]; uint4 v; } ph, pl;
        #pragma unroll
        for (int i=0;i<8;++i){
          float y = *(const float*)(strip + ((b*8+i)*4 + (r>>2))*16 + (r&3)*4);
          ph.s[i] = f2bf(y);
          if constexpr (SPLIT) pl.s[i] = f2bf(y - bf2f(ph.s[i]));
        }
        size_t idx = ((size_t)e*256 + grow)*N + n0 + wn*(BN/4) + b*8;
        *(uint4*)(Ohi + idx) = ph.v;
        if constexpr (SPLIT) *(uint4*)(Olo + idx) = pl.v;
      } else {
        #pragma unroll
        for (int cc=0; cc<NI; ++cc){
          int c = b + cc*4;
          float4 o;
          o.x = *(const float*)(strip + ((c*4+0)*4 + (r>>2))*16 + (r&3)*4);
          o.y = *(const float*)(strip + ((c*4+1)*4 + (r>>2))*16 + (r&3)*4);
          o.z = *(const float*)(strip + ((c*4+2)*4 + (r>>2))*16 + (r&3)*4);
          o.w = *(const float*)(strip + ((c*4+3)*4 + (r>>2))*16 + (r&3)*4);
          *(float4*)(Of + ((size_t)e*256 + grow)*N + n0 + wn*(BN/4) + c*4) = o;
        }
      }
      asm volatile("s_waitcnt lgkmcnt(0)" ::: "memory");
    }
  }
}

// ---------------- combine (optionally fused RMSNorm -> bf16) ----------------
template<bool FINAL>
__global__ __launch_bounds__(256) void k_combine(float* __restrict__ h,
    const float* __restrict__ Y2, const int* __restrict__ top2,
    const float* __restrict__ p2, const int* __restrict__ kept,
    const float* __restrict__ g, u16* __restrict__ hn){
  int t = blockIdx.x;
  int e0 = top2[t*2], e1 = top2[t*2+1];
  int r0 = kept[t*2], r1 = kept[t*2+1];
  float w0 = (r0 >= 0) ? p2[t*2]   : 0.f;
  float w1 = (r1 >= 0) ? p2[t*2+1] : 0.f;
  float om = 1.f - w0 - w1;
  int d = threadIdx.x * 4;
  float4 v = *(const float4*)(h + (size_t)t*D_ + d);
  float ox = v.x*om, oy = v.y*om, oz = v.z*om, ow = v.w*om;
  if (r0 >= 0){
    float4 y = *(const float4*)(Y2 + ((size_t)e0*CAP_ + r0)*D_ + d);
    ox += w0*y.x; oy += w0*y.y; oz += w0*y.z; ow += w0*y.w;
  }
  if (r1 >= 0){
    float4 y = *(const float4*)(Y2 + ((size_t)e1*CAP_ + r1)*D_ + d);
    ox += w1*y.x; oy += w1*y.y; oz += w1*y.z; ow += w1*y.w;
  }
  if constexpr (!FINAL){
    *(float4*)(h + (size_t)t*D_ + d) = make_float4(ox, oy, oz, ow);
  } else {
    int w = threadIdx.x >> 6, l = threadIdx.x & 63;
    __shared__ float red[4];
    float ss = ox*ox + oy*oy + oz*oz + ow*ow;
    #pragma unroll
    for (int off=32; off; off>>=1) ss += __shfl_xor(ss, off, 64);
    if (l == 0) red[w] = ss;
    __syncthreads();
    float tot = red[0] + red[1] + red[2] + red[3];
    float sc = rsqrtf(tot * (1.f/D_) + 1e-5f);
    float4 gs = *(const float4*)(g + d);
    union { u16 s[4]; uint2 u; } o;
    o.s[0] = f2bf(ox*sc*gs.x); o.s[1] = f2bf(oy*sc*gs.y);
    o.s[2] = f2bf(oz*sc*gs.z); o.s[3] = f2bf(ow*sc*gs.w);
    *(uint2*)(hn + (size_t)t*D_ + d) = o.u;
  }
}

// ---------------- final GEMM: exact R4 revert (best known: 172 us) ----------------
#define SLOT_ 16384
__global__ __launch_bounds__(512, 2) void k_gemm_final(const u16* __restrict__ A,
    const u16* __restrict__ B, float* __restrict__ C){
  __shared__ __align__(16) char lds[131072];
  char* ldsA = lds;
  char* ldsB = lds + 65536;
  int bid = blockIdx.x;
  int wgid = (bid & 7) * 125 + (bid >> 3);
  int m0 = (wgid & 7) << 8;
  int n0 = (wgid >> 3) << 8;
  int tid = threadIdx.x;
  int lane = tid & 63;
  int w = tid >> 6;
  int wm = w >> 2, wn = w & 3;
  int lr = lane & 15, lq = lane >> 4;

  f32x4 acc[8][4];
  #pragma unroll
  for (int i=0;i<8;++i)
    #pragma unroll
    for (int j=0;j<4;++j)
      #pragma unroll
      for (int c=0;c<4;++c) acc[i][j][c] = 0.f;

  int j_0 = w*2, j_1 = w*2 + 1;
  int rp0 = j_0*8 + (lane>>3), rp1 = j_1*8 + (lane>>3);
  int c80 = (lane&7) ^ (rp0&7), c81 = (lane&7) ^ (rp1&7);
  int rA0 = rp0*2 + (c80>>2), rA1 = rp1*2 + (c81>>2);
  int cc0 = (c80&3)*8,        cc1 = (c81&3)*8;
  const u16* sA0 = A + (size_t)(m0+rA0)*D_ + cc0;
  const u16* sA1 = A + (size_t)(m0+rA1)*D_ + cc1;
  const u16* sB0 = B + (size_t)(n0+rA0)*D_ + cc0;
  const u16* sB1 = B + (size_t)(n0+rA1)*D_ + cc1;
  int d0 = j_0*1024 + lane*16, d1 = j_1*1024 + lane*16;

  int aoff[8], boff[4];
  #pragma unroll
  for (int mi=0;mi<8;++mi){
    int r = wm*128 + mi*16 + lr;
    int rp = r >> 1;
    int c8 = ((r&1)<<2) | lq;
    aoff[mi] = rp*128 + ((c8 ^ (rp&7))<<4);
  }
  #pragma unroll
  for (int ni=0;ni<4;++ni){
    int r = wn*64 + ni*16 + lr;
    int rp = r >> 1;
    int c8 = ((r&1)<<2) | lq;
    boff[ni] = rp*128 + ((c8 ^ (rp&7))<<4);
  }

  #define STAGE_(sbase) do { \
    gl_lds16(sA0, ldsA + (sbase) + d0); gl_lds16(sB0, ldsB + (sbase) + d0); \
    gl_lds16(sA1, ldsA + (sbase) + d1); gl_lds16(sB1, ldsB + (sbase) + d1); \
    sA0 += 32; sA1 += 32; sB0 += 32; sB1 += 32; } while(0)

  bf16x8 aF0[8], bF0[4], aF1[8], bF1[4];

  STAGE_(0); STAGE_(SLOT_); STAGE_(2*SLOT_);
  asm volatile("s_waitcnt vmcnt(8)" ::: "memory");
  __builtin_amdgcn_s_barrier();
  {
    const char* pA_ = ldsA; const char* pB_ = ldsB;
    #pragma unroll
    for (int ni=0;ni<4;++ni) bF0[ni] = *(const bf16x8*)(pB_ + boff[ni]);
    #pragma unroll
    for (int mi=0;mi<8;++mi) aF0[mi] = *(const bf16x8*)(pA_ + aoff[mi]);
  }

  #define PHASE_(kh, FAc, FBc, FAn, FBn) do { \
    if ((kh) <= 28) STAGE_((((kh)+3)&3)*SLOT_); \
    if ((kh) <= 28)      asm volatile("s_waitcnt vmcnt(8)" ::: "memory"); \
    else if ((kh) == 29) asm volatile("s_waitcnt vmcnt(4)" ::: "memory"); \
    else if ((kh) == 30) asm volatile("s_waitcnt vmcnt(0)" ::: "memory"); \
    asm volatile("s_waitcnt lgkmcnt(0)" ::: "memory"); \
    __builtin_amdgcn_sched_barrier(0); \
    __builtin_amdgcn_s_barrier(); \
    __builtin_amdgcn_sched_barrier(0); \
    if ((kh) < 31){ \
      int sb_ = (((kh)+1)&3)*SLOT_; \
      const char* pA_ = ldsA + sb_; const char* pB_ = ldsB + sb_; \
      _Pragma("unroll") for (int ni=0;ni<4;++ni) FBn[ni] = *(const bf16x8*)(pB_ + boff[ni]); \
      _Pragma("unroll") for (int mi=0;mi<8;++mi) FAn[mi] = *(const bf16x8*)(pA_ + aoff[mi]); \
    } \
    __builtin_amdgcn_s_setprio(1); \
    _Pragma("unroll") for (int mi=0;mi<8;++mi){ \
      _Pragma("unroll") for (int ni=0;ni<4;++ni) \
        acc[mi][ni] = mfma16(FAc[mi], FBc[ni], acc[mi][ni]); \
    } \
    __builtin_amdgcn_s_setprio(0); \
  } while(0)

  for (int kh2 = 0; kh2 < 32; kh2 += 2){
    PHASE_(kh2,     aF0, bF0, aF1, bF1);
    PHASE_(kh2 + 1, aF1, bF1, aF0, bF0);
  }
  #undef PHASE_
  #undef STAGE_

  #pragma unroll
  for (int mi=0;mi<8;++mi)
    #pragma unroll
    for (int ni=0;ni<4;++ni)
      #pragma unroll
      for (int j=0;j<4;++j){
        int row = m0 + wm*128 + mi*16 + lq*4 + j;
        int col = n0 + wn*64 + ni*16 + lr;
        C[(size_t)row * V_ + col] = acc[mi][ni][j];
      }
}

extern "C" void kernel_launch(void* const* d_in, const int* in_sizes, int n_in,
                              void* d_out, int out_size, void* d_ws, size_t ws_size,
                              hipStream_t stream){
  const int*   ids  = (const int*)d_in[0];
  const float* embW = (const float*)d_in[1];
  const float* lns  = (const float*)d_in[2];
  const float* WrA  = (const float*)d_in[3];
  const float* W1A  = (const float*)d_in[4];
  const float* W2A  = (const float*)d_in[5];
  float* out = (float*)d_out;
  char* ws = (char*)d_ws;
  const size_t MB = 1u << 20;

  float* h      = (float*)(ws);
  float* logits = (float*)(ws + 8*MB);
  unsigned char* mask = (unsigned char*)(ws + 8*MB + 131072);
  int*   top2v  = (int*)(ws + 8*MB + 131072 + 32768);
  float* p2     = (float*)(ws + 8*MB + 131072 + 32768 + 16384);
  int*   kept   = (int*)(ws + 8*MB + 131072 + 32768 + 32768);
  int*   etok   = (int*)(ws + 8*MB + 131072 + 32768 + 49152);
  u16*   xhi  = (u16*)(ws + 9*MB);
  u16*   xlo  = (u16*)(ws + 17*MB);
  float* y2   = (float*)(ws + 9*MB);            // aliases xhi/xlo (dead by then)
  u16*   y1hi = (u16*)(ws + 25*MB);
  u16*   y1lo = (u16*)(ws + 41*MB);
  u16*   hn   = (u16*)(ws + 57*MB);
  u16*   ebf  = (u16*)(ws + 61*MB);

  k_cvtw<<<(V_*D_)/(256*8), 256, 0, stream>>>(embW, ebf);

  for (int hop = 0; hop < 2; ++hop){
    const float* Wr = WrA + (size_t)hop*D_*E_;
    const float* W1 = W1A + (size_t)hop*E_*D_*DFF_;
    const float* W2 = W2A + (size_t)hop*E_*DFF_*D_;
    if (hop == 0){
      k_router<true ><<<T_/4, 256, 0, stream>>>(h, Wr, logits, mask, top2v, p2, ids, embW, etok);
      k_capacity<<<T_*2/4, 256, 0, stream>>>(logits, mask, top2v, kept, etok);
      k_gather<true ><<<E_*CAP_, 256, 0, stream>>>(h, etok, xhi, xlo);
      k_expert<true , true , 128><<<E_*2*(DFF_/128), 512, 0, stream>>>(
          xhi, xlo, W1, y1hi, y1lo, nullptr, DFF_, D_);
      k_expert<true , false, 64 ><<<E_*2*(D_/64), 512, 0, stream>>>(
          y1hi, y1lo, W2, nullptr, nullptr, y2, D_, DFF_);
      k_combine<false><<<T_, 256, 0, stream>>>(h, y2, top2v, p2, kept, lns, hn);
    } else {
      k_router<false><<<T_/4, 256, 0, stream>>>(h, Wr, logits, mask, top2v, p2, ids, embW, etok);
      k_capacity<<<T_*2/4, 256, 0, stream>>>(logits, mask, top2v, kept, etok);
      k_gather<false><<<E_*CAP_, 256, 0, stream>>>(h, etok, xhi, xlo);
      k_expert<false, true , 128><<<E_*2*(DFF_/128), 512, 0, stream>>>(
          xhi, nullptr, W1, y1hi, nullptr, nullptr, DFF_, D_);
      k_expert<false, false, 64 ><<<E_*2*(D_/64), 512, 0, stream>>>(
          y1hi, nullptr, W2, nullptr, nullptr, y2, D_, DFF_);
      k_combine<true ><<<T_, 256, 0, stream>>>(h, y2, top2v, p2, kept, lns, hn);
    }
  }

  k_gemm_final<<<(T_/256)*(V_/256), 512, 0, stream>>>(hn, ebf, out);
}